// Round 1
// baseline (86.376 us; speedup 1.0000x reference)
//
#include <hip/hip_runtime.h>

// Quanvolution (K=2, 4 qubits) collapsed to closed form:
//   z_q = cos(pi*v_q + w_q),  v_q = input pixel at patch offset (q>>1, q&1)
//   out0 = z1*z2*z3; out1 = z0*z1; out2 = z0*z1*z2; out3 = z0*z1*z2*z3
// Derivation: RY(w)RY(theta)|0> = RY(theta+w)|0>; CNOT ring is a GF(2)-linear
// basis permutation; <Z_q> factorizes over independent qubit bits.

constexpr int H = 224, W = 224;
constexpr int LX = 223, LY = 223;
constexpr long long PLANE = (long long)LX * LY;

__global__ __launch_bounds__(256) void quanv_kernel(
    const float* __restrict__ in,   // (B,1,224,224)
    const float* __restrict__ wt,   // (1,4)
    float* __restrict__ out)        // (B,4,223,223)
{
    __shared__ float cw[4], sw[4];
    if (threadIdx.x < 4) {
        float s, c;
        sincosf(wt[threadIdx.x], &s, &c);
        sw[threadIdx.x] = s;
        cw[threadIdx.x] = c;
    }
    __syncthreads();

    const int y = threadIdx.x;   // 0..255, valid < 223
    const int x = blockIdx.x;    // 0..222
    const int b = blockIdx.y;    // batch
    if (y >= LY) return;

    const float* p = in + ((size_t)b * H + x) * W + y;
    const float v00 = p[0];
    const float v01 = p[1];
    const float v10 = p[W];
    const float v11 = p[W + 1];

    // sin(pi*v), cos(pi*v) exactly via sincospif, then angle addition:
    // cos(pi*v + w) = cos(pi*v)*cos(w) - sin(pi*v)*sin(w)
    float s0, c0, s1, c1, s2, c2, s3, c3;
    sincospif(v00, &s0, &c0);
    sincospif(v01, &s1, &c1);
    sincospif(v10, &s2, &c2);
    sincospif(v11, &s3, &c3);

    const float z0 = fmaf(c0, cw[0], -(s0 * sw[0]));
    const float z1 = fmaf(c1, cw[1], -(s1 * sw[1]));
    const float z2 = fmaf(c2, cw[2], -(s2 * sw[2]));
    const float z3 = fmaf(c3, cw[3], -(s3 * sw[3]));

    const float o1 = z0 * z1;
    const float o2 = o1 * z2;
    const float o3 = o2 * z3;
    const float o0 = z1 * (z2 * z3);

    float* o = out + (size_t)b * 4 * PLANE + (size_t)x * LY + y;
    o[0]         = o0;
    o[PLANE]     = o1;
    o[2 * PLANE] = o2;
    o[3 * PLANE] = o3;
}

extern "C" void kernel_launch(void* const* d_in, const int* in_sizes, int n_in,
                              void* d_out, int out_size, void* d_ws, size_t ws_size,
                              hipStream_t stream) {
    const float* in = (const float*)d_in[0];
    const float* wt = (const float*)d_in[1];
    float* out = (float*)d_out;

    const int B = in_sizes[0] / (H * W);   // 64
    dim3 grid(LX, B);                       // one block per (row, batch)
    quanv_kernel<<<grid, 256, 0, stream>>>(in, wt, out);
}

// Round 2
// 81.322 us; speedup vs baseline: 1.0622x; 1.0622x over previous
//
#include <hip/hip_runtime.h>

// Quanvolution (K=2, 4 qubits) collapsed to closed form:
//   z_q = cos(pi*v_q + w_q),  v_q = pixel at patch offset (q>>1, q&1)
//   out0 = z1*z2*z3; out1 = z0*z1; out2 = z0*z1*z2; out3 = z0*z1*z2*z3
// Derivation: RY(w)RY(theta)|0> = RY(theta+w)|0>; CNOT ring is GF(2)-linear
// on basis bits; <Z_q> factorizes over independent qubit bits.
//
// cos evaluated as cos(2*pi*u), u = v/2 + w/(2*pi):
//   uf = u - rint(u) in [-0.5,0.5]; cos(2*pi*uf) = 1 - 2*sin^2(pi*uf),
//   sin via deg-11 Taylor on [-pi/2,pi/2] (abs err ~6e-8).

constexpr int H = 224, W = 224;
constexpr int LX = 223, LY = 223;
constexpr int PLANE = LX * LY;          // 49729

__device__ __forceinline__ float cos2pi(float u) {
    float uf = u - rintf(u);                 // [-0.5, 0.5]
    float t  = uf * 3.14159265358979f;       // [-pi/2, pi/2]
    float t2 = t * t;
    float q = -2.5052108e-8f;
    q = fmaf(q, t2,  2.7557319e-6f);
    q = fmaf(q, t2, -1.9841270e-4f);
    q = fmaf(q, t2,  8.3333333e-3f);
    q = fmaf(q, t2, -0.16666667f);
    float s = fmaf(t * t2, q, t);            // sin(pi*uf)
    return fmaf(-2.0f * s, s, 1.0f);         // cos(2*pi*u)
}

__global__ __launch_bounds__(256) void quanv_kernel(
    const float* __restrict__ in,   // (B,1,224,224)
    const float* __restrict__ wt,   // (1,4)
    float* __restrict__ out,        // (B,4,223,223)
    int total)                      // B*PLANE
{
    const int n = blockIdx.x * 256 + threadIdx.x;
    if (n >= total) return;

    const int b = n / PLANE;
    const int r = n - b * PLANE;
    const int x = r / LY;
    const int y = r - x * LY;

    const float* p = in + ((size_t)b * H + x) * W + y;
    const float v0 = p[0];
    const float v1 = p[1];
    const float v2 = p[W];
    const float v3 = p[W + 1];

    constexpr float inv2pi = 0.15915494309189535f;
    const float w0 = wt[0] * inv2pi;
    const float w1 = wt[1] * inv2pi;
    const float w2 = wt[2] * inv2pi;
    const float w3 = wt[3] * inv2pi;

    const float z0 = cos2pi(fmaf(v0, 0.5f, w0));
    const float z1 = cos2pi(fmaf(v1, 0.5f, w1));
    const float z2 = cos2pi(fmaf(v2, 0.5f, w2));
    const float z3 = cos2pi(fmaf(v3, 0.5f, w3));

    const float o1 = z0 * z1;
    const float o2 = o1 * z2;
    const float o3 = o2 * z3;
    const float o0 = z1 * (z2 * z3);

    float* o = out + (size_t)b * 4 * PLANE + (size_t)x * LY + y;
    o[0]             = o0;
    o[PLANE]         = o1;
    o[2 * PLANE]     = o2;
    o[3 * PLANE]     = o3;
}

extern "C" void kernel_launch(void* const* d_in, const int* in_sizes, int n_in,
                              void* d_out, int out_size, void* d_ws, size_t ws_size,
                              hipStream_t stream) {
    const float* in = (const float*)d_in[0];
    const float* wt = (const float*)d_in[1];
    float* out = (float*)d_out;

    const int B = in_sizes[0] / (H * W);          // 64
    const int total = B * PLANE;
    const int grid = (total + 255) / 256;
    quanv_kernel<<<grid, 256, 0, stream>>>(in, wt, out, total);
}

// Round 5
// 79.313 us; speedup vs baseline: 1.0891x; 1.0253x over previous
//
#include <hip/hip_runtime.h>

// Quanvolution (K=2, 4 qubits) collapsed to closed form:
//   z_q = cos(pi*v_q + w_q),  v_q = pixel at patch offset (q>>1, q&1)
//   out0 = z1*z2*z3; out1 = z0*z1; out2 = z0*z1*z2; out3 = z0*z1*z2*z3
// Derivation: RY(w)RY(theta)|0> = RY(theta+w)|0>; CNOT ring is GF(2)-linear
// on basis bits; <Z_q> factorizes over independent qubit bits.
//
// 4-wide along y: each thread computes 4 consecutive output pixels of one
// row (chunk). Loads: float4 (aligned) + 1 scalar per input row. Stores:
// 16B per plane via memcpy (global_store_dwordx4, dword-aligned OK on gfx950).

constexpr int H = 224, W = 224;
constexpr int LX = 223, LY = 223;
constexpr int PLANE = LX * LY;          // 49729
constexpr int CPR = 56;                 // chunks per row (ceil(223/4)), last=3 wide

typedef float f4 __attribute__((ext_vector_type(4)));

__device__ __forceinline__ float cos2pi(float u) {
    float uf = u - rintf(u);                 // [-0.5, 0.5]
    float t  = uf * 3.14159265358979f;       // [-pi/2, pi/2]
    float t2 = t * t;
    float q = -2.5052108e-8f;
    q = fmaf(q, t2,  2.7557319e-6f);
    q = fmaf(q, t2, -1.9841270e-4f);
    q = fmaf(q, t2,  8.3333333e-3f);
    q = fmaf(q, t2, -0.16666667f);
    float s = fmaf(t * t2, q, t);            // sin(pi*uf)
    return fmaf(-2.0f * s, s, 1.0f);         // cos(2*pi*u)
}

__global__ __launch_bounds__(256) void quanv_kernel(
    const float* __restrict__ in,   // (B,1,224,224)
    const float* __restrict__ wt,   // (1,4)
    float* __restrict__ out)        // (B,4,223,223)
{
    const int c = blockIdx.x * 256 + threadIdx.x;   // chunk id, exact grid
    const int b = c / (LX * CPR);
    const int r = c - b * (LX * CPR);
    const int x = r / CPR;
    const int k = r - x * CPR;
    const int cy = k * 4;
    const bool tail = (k == CPR - 1);               // outputs 220..222 only

    const float* p = in + ((size_t)b * H + x) * W + cy;   // 16B-aligned
    const f4 tv = *(const f4*)p;                           // top pixels cy..cy+3
    const f4 bv = *(const f4*)(p + W);                     // bottom pixels
    // pixel cy+4 needed only for non-tail chunks (tail would read 4B OOB at
    // the very last chunk of the array)
    const int i4 = tail ? 3 : 4;
    const float t4 = p[i4];
    const float b4 = p[W + i4];

    constexpr float inv2pi = 0.15915494309189535f;
    const float w0 = wt[0] * inv2pi;
    const float w1 = wt[1] * inv2pi;
    const float w2 = wt[2] * inv2pi;
    const float w3 = wt[3] * inv2pi;

    const float t_[5] = {tv.x, tv.y, tv.z, tv.w, t4};
    const float b_[5] = {bv.x, bv.y, bv.z, bv.w, b4};

    f4 o0, o1, o2, o3;
    #pragma unroll
    for (int i = 0; i < 4; ++i) {
        const float z0 = cos2pi(fmaf(t_[i],     0.5f, w0));
        const float z1 = cos2pi(fmaf(t_[i + 1], 0.5f, w1));
        const float z2 = cos2pi(fmaf(b_[i],     0.5f, w2));
        const float z3 = cos2pi(fmaf(b_[i + 1], 0.5f, w3));
        const float p1 = z0 * z1;
        const float p2 = p1 * z2;
        o0[i] = z1 * (z2 * z3);
        o1[i] = p1;
        o2[i] = p2;
        o3[i] = p2 * z3;
    }

    float* o = out + (size_t)b * 4 * PLANE + x * LY + cy;
    if (!tail) {
        __builtin_memcpy(o,             &o0, 16);
        __builtin_memcpy(o + PLANE,     &o1, 16);
        __builtin_memcpy(o + 2 * PLANE, &o2, 16);
        __builtin_memcpy(o + 3 * PLANE, &o3, 16);
    } else {
        #pragma unroll
        for (int i = 0; i < 3; ++i) {
            o[i]             = o0[i];
            o[PLANE + i]     = o1[i];
            o[2 * PLANE + i] = o2[i];
        }
        #pragma unroll
        for (int i = 0; i < 3; ++i) {
            o[3 * PLANE + i] = o3[i];
        }
    }
}

extern "C" void kernel_launch(void* const* d_in, const int* in_sizes, int n_in,
                              void* d_out, int out_size, void* d_ws, size_t ws_size,
                              hipStream_t stream) {
    const float* in = (const float*)d_in[0];
    const float* wt = (const float*)d_in[1];
    float* out = (float*)d_out;

    const int B = in_sizes[0] / (H * W);          // 64
    const int total = B * LX * CPR;               // 799232, divisible by 256
    quanv_kernel<<<total / 256, 256, 0, stream>>>(in, wt, out);
}